// Round 4
// baseline (2282.504 us; speedup 1.0000x reference)
//
#include <hip/hip_runtime.h>
#include <stdint.h>

// z: [16,1024,256] fp32 -> N=16384 rows, D=256
// embedding: [8192,256] fp32 -> K=8192 codes
// out = [ z_q (4194304 f32) | loss (1 f32) | indices (16384 as f32) ]
#define N_ROWS   16384
#define DIM      256
#define N_CODES  8192
#define ZQ_ELEMS 4194304

typedef _Float16 f16x8 __attribute__((ext_vector_type(8)));
typedef _Float16 f16x4 __attribute__((ext_vector_type(4)));
typedef float    f32x16 __attribute__((ext_vector_type(16)));
typedef unsigned long long u64;

// ---- workspace (bytes): e_tiled 8 MB | norms 32 KB | pkeys 4 MB ----
#define WS_ET  0
#define WS_NRM (8388608)
#define WS_PK  (8421376)
// z tiled f16 planes live in the d_out z_q region (exactly 16 MB = 64 slabs
// x 16384 rows x 16 B), overwritten by vq_final after all reads (stream order).

static __device__ __forceinline__ void glds16(const void* gsrc, void* ldst) {
    __builtin_amdgcn_global_load_lds(
        (const __attribute__((address_space(1))) unsigned int*)gsrc,
        (__attribute__((address_space(3))) unsigned int*)ldst,
        16, 0, 0);
}

static __device__ __forceinline__ u64 packkey(float d, int c) {
    unsigned int u = __float_as_uint(d);
    u ^= ((unsigned int)((int)u >> 31)) | 0x80000000u;   // monotone float map
    return ((u64)u << 32) | (unsigned int)c;             // min => (dist, then idx)
}

// ---------------- prep E: norms + fragment-major tiled f16 hi/lo ----------------
// et 16-B units: slab = p*32 + dk*4 + f (p=plane, dk=K-chunk of 32, f=8-half group);
// unit addr = slab*8192 + code.
__global__ void vq_prep_e(const float* __restrict__ emb,
                          _Float16* __restrict__ et,
                          float* __restrict__ norms, float* __restrict__ loss_ptr) {
    if (blockIdx.x == 0 && threadIdx.x == 0) *loss_ptr = 0.0f;
    __shared__ _Float16 lh[4][256];
    __shared__ _Float16 ll[4][256];
    const int t = threadIdx.x, w = t >> 6, l = t & 63;
    const int code = blockIdx.x * 4 + w;
    float4 v = *(const float4*)(emb + (size_t)code * DIM + l * 4);
    float xs[4] = {v.x, v.y, v.z, v.w};
    f16x4 hh, lo;
    float s = 0.0f;
    #pragma unroll
    for (int i = 0; i < 4; ++i) {
        _Float16 h = (_Float16)xs[i];
        hh[i] = h;
        lo[i] = (_Float16)(xs[i] - (float)h);
        s += xs[i] * xs[i];
    }
    *(f16x4*)&lh[w][l * 4] = hh;
    *(f16x4*)&ll[w][l * 4] = lo;
    #pragma unroll
    for (int off = 32; off > 0; off >>= 1) s += __shfl_down(s, off, 64);
    if (l == 0) norms[code] = s;
    __syncthreads();
    const int p = t >> 7, g = t & 127;           // 2 planes x 4 codes x 32 slabs/plane
    const int cl = g & 3, dk = (g >> 2) & 7, f = g >> 5;
    f16x8 frag = (p == 0) ? *(const f16x8*)&lh[cl][dk * 32 + f * 8]
                          : *(const f16x8*)&ll[cl][dk * 32 + f * 8];
    const size_t slab = (size_t)(p * 32 + dk * 4 + f);
    *(f16x8*)(et + (slab * N_CODES + blockIdx.x * 4 + cl) * 8) = frag;
}

// ---------------- prep Z: fragment-major tiled f16 hi/lo (into zq region) ----------------
// zt 16-B units: slab = p*32 + dk*4 + f; unit addr = slab*16384 + row.
// 64 rows per block; LDS transpose so global writes are 1 KB contiguous per wave.
__global__ void vq_prep_z(const float* __restrict__ z, _Float16* __restrict__ zt) {
    __shared__ _Float16 ls[2][64][256];          // 64 KB
    const int t = threadIdx.x, w = t >> 6, l = t & 63;
    const int row0 = blockIdx.x * 64;
    #pragma unroll
    for (int j = 0; j < 16; ++j) {
        const int row = w * 16 + j;
        float4 v = *(const float4*)(z + (size_t)(row0 + row) * DIM + l * 4);
        float xs[4] = {v.x, v.y, v.z, v.w};
        f16x4 hh, lo;
        #pragma unroll
        for (int i = 0; i < 4; ++i) {
            _Float16 h = (_Float16)xs[i];
            hh[i] = h;
            lo[i] = (_Float16)(xs[i] - (float)h);
        }
        *(f16x4*)&ls[0][row][l * 4] = hh;
        *(f16x4*)&ls[1][row][l * 4] = lo;
    }
    __syncthreads();
    #pragma unroll
    for (int pass = 0; pass < 16; ++pass) {
        const int slab = pass * 4 + w;           // p*32 + dk*4 + f
        const int p = slab >> 5, dk = (slab >> 2) & 7, f = slab & 3;
        f16x8 frag = *(const f16x8*)&ls[p][l][dk * 32 + f * 8];
        *(f16x8*)(zt + ((size_t)slab * N_ROWS + row0 + l) * 8) = frag;
    }
}

// ---------------- main: m97 2-barrier K-loop, both tiles via glds ----------------
// grid 4096 = 128 row-blocks x 32 code-blocks; 4 waves; wave tile 64x128 (rt2 x ct4).
// LDS 49152 B: z [p2][f4][128 rows] @0, e [p2][f4][256 codes] @16384.
__global__ __launch_bounds__(256, 3)
void vq_main(const _Float16* __restrict__ zt, const _Float16* __restrict__ et,
             const float* __restrict__ norms, u64* __restrict__ pkeys) {
    extern __shared__ char smem[];
    const int tid = threadIdx.x;
    const int w = tid >> 6, L = tid & 63, lo5 = L & 31, hi1 = L >> 5;
    const int rw = w & 1, cw = w >> 1;
    const int rb = blockIdx.x & 127, cb = blockIdx.x >> 7;
    const int row0 = rb * 128, code0 = cb * 256;

    f32x16 acc[2][4];
    #pragma unroll
    for (int rt = 0; rt < 2; ++rt)
        #pragma unroll
        for (int ct = 0; ct < 4; ++ct)
            #pragma unroll
            for (int e = 0; e < 16; ++e) acc[rt][ct][e] = 0.0f;

    for (int dk = 0; dk < 8; ++dk) {
        __syncthreads();                         // prior frag reads done
        // stage 48 KB: 48 glds of 1 KB, 12 per wave
        #pragma unroll
        for (int i = 0; i < 12; ++i) {
            const int idx = w * 12 + i;
            if (idx < 16) {                      // z tile: p2 x f4 x sub2
                const int p = idx >> 3, f = (idx >> 1) & 3, sub = idx & 1;
                const _Float16* g = zt + ((size_t)(p * 32 + dk * 4 + f) * N_ROWS
                                          + row0 + sub * 64 + L) * 8;
                glds16(g, smem + ((p * 4 + f) * 128 + sub * 64) * 16);
            } else {                             // e tile: p2 x f4 x sub4
                const int j = idx - 16;
                const int p = j >> 4, f = (j >> 2) & 3, sub = j & 3;
                const _Float16* g = et + ((size_t)(p * 32 + dk * 4 + f) * N_CODES
                                          + code0 + sub * 64 + L) * 8;
                glds16(g, smem + 16384 + ((p * 4 + f) * 256 + sub * 64) * 16);
            }
        }
        __syncthreads();                         // vmcnt drain -> tiles visible

        #pragma unroll
        for (int ks = 0; ks < 2; ++ks) {
            const int fs = ks * 2 + hi1;
            f16x8 ah[2], al[2], bh[4], bl[4];
            #pragma unroll
            for (int rt = 0; rt < 2; ++rt) {
                const int off = (fs * 128 + rw * 64 + rt * 32 + lo5) * 16;
                ah[rt] = *(const f16x8*)(smem + off);
                al[rt] = *(const f16x8*)(smem + 8192 + off);
            }
            #pragma unroll
            for (int ct = 0; ct < 4; ++ct) {
                const int off = 16384 + (fs * 256 + cw * 128 + ct * 32 + lo5) * 16;
                bh[ct] = *(const f16x8*)(smem + off);
                bl[ct] = *(const f16x8*)(smem + 16384 + off);
            }
            #pragma unroll
            for (int rt = 0; rt < 2; ++rt)
                #pragma unroll
                for (int ct = 0; ct < 4; ++ct) {
                    acc[rt][ct] = __builtin_amdgcn_mfma_f32_32x32x16_f16(ah[rt], bh[ct], acc[rt][ct], 0, 0, 0);
                    acc[rt][ct] = __builtin_amdgcn_mfma_f32_32x32x16_f16(ah[rt], bl[ct], acc[rt][ct], 0, 0, 0);
                    acc[rt][ct] = __builtin_amdgcn_mfma_f32_32x32x16_f16(al[rt], bh[ct], acc[rt][ct], 0, 0, 0);
                }
        }
    }

    // ---- argmin: pack -> u64, butterfly over 32 code-lanes, merge code halves ----
    __syncthreads();
    u64* sc = (u64*)smem;                        // [4][64]
    const int cbase = code0 + cw * 128 + lo5;
    float nrm[4];
    #pragma unroll
    for (int ct = 0; ct < 4; ++ct) nrm[ct] = norms[cbase + ct * 32];
    #pragma unroll
    for (int rt = 0; rt < 2; ++rt)
        #pragma unroll
        for (int reg = 0; reg < 16; ++reg) {
            u64 k = packkey(nrm[0] - 2.0f * acc[rt][0][reg], cbase);
            #pragma unroll
            for (int ct = 1; ct < 4; ++ct) {
                u64 o = packkey(nrm[ct] - 2.0f * acc[rt][ct][reg], cbase + ct * 32);
                if (o < k) k = o;
            }
            u64 o;
            o = __shfl_xor(k, 1, 64);  if (o < k) k = o;
            o = __shfl_xor(k, 2, 64);  if (o < k) k = o;
            o = __shfl_xor(k, 4, 64);  if (o < k) k = o;
            o = __shfl_xor(k, 8, 64);  if (o < k) k = o;
            o = __shfl_xor(k, 16, 64); if (o < k) k = o;
            if (lo5 == 0)
                sc[w * 64 + rt * 32 + (reg & 3) + 8 * (reg >> 2) + 4 * hi1] = k;
        }
    __syncthreads();
    if (tid < 128) {                             // row = tid; waves h and h+2 cover it
        const int h = tid >> 6, r6 = tid & 63;
        u64 k = sc[h * 64 + r6];
        u64 o = sc[(h + 2) * 64 + r6];
        if (o < k) k = o;
        pkeys[(size_t)cb * N_ROWS + row0 + tid] = k;
    }
}

// ---------------- final: merge 32 partials, idx, z_q gather, loss ----------------
__global__ __launch_bounds__(512)
void vq_final(const float* __restrict__ z, const float* __restrict__ emb,
              const u64* __restrict__ pkeys,
              float* __restrict__ zq_out, float* __restrict__ loss_out,
              float* __restrict__ idx_out) {
    __shared__ u64 kk[8][64];
    __shared__ int best[64];
    const int t = threadIdx.x;
    const int row0 = blockIdx.x * 64;
    const int r = t & 63, j = t >> 6;
    u64 k = ~0ULL;
    #pragma unroll
    for (int q = 0; q < 4; ++q) {
        u64 o = pkeys[(size_t)(j * 4 + q) * N_ROWS + row0 + r];
        if (o < k) k = o;
    }
    kk[j][r] = k;
    __syncthreads();
    if (t < 64) {
        u64 kb = kk[0][t];
        #pragma unroll
        for (int j2 = 1; j2 < 8; ++j2) if (kk[j2][t] < kb) kb = kk[j2][t];
        int code = (int)(kb & 0xFFFFFFFFu);
        best[t] = code;
        idx_out[row0 + t] = (float)code;
    }
    __syncthreads();
    const int wave = t >> 6, lane = t & 63;
    float lsum = 0.0f;
    #pragma unroll
    for (int rr = 0; rr < 8; ++rr) {
        const int rl = wave * 8 + rr;
        const int rg = row0 + rl;
        const int code = best[rl];
        float4 ev = *(const float4*)(emb + (size_t)code * DIM + lane * 4);
        float4 zv = *(const float4*)(z   + (size_t)rg   * DIM + lane * 4);
        float dx = ev.x - zv.x, dy = ev.y - zv.y;
        float dz = ev.z - zv.z, dw = ev.w - zv.w;
        lsum += dx * dx + dy * dy + dz * dz + dw * dw;
        *(float4*)(zq_out + (size_t)rg * DIM + lane * 4) = ev;
    }
    #pragma unroll
    for (int off = 32; off > 0; off >>= 1) lsum += __shfl_down(lsum, off, 64);
    if (lane == 0) atomicAdd(loss_out, lsum * (1.25f / (float)ZQ_ELEMS));
}

extern "C" void kernel_launch(void* const* d_in, const int* in_sizes, int n_in,
                              void* d_out, int out_size, void* d_ws, size_t ws_size,
                              hipStream_t stream) {
    const float* z   = (const float*)d_in[0];
    const float* emb = (const float*)d_in[1];
    float* out  = (float*)d_out;
    float* zq   = out;
    float* loss = out + ZQ_ELEMS;
    float* idx  = out + ZQ_ELEMS + 1;

    char* ws = (char*)d_ws;
    _Float16* et = (_Float16*)(ws + WS_ET);
    float* norms = (float*)(ws + WS_NRM);
    u64*   pk    = (u64*)(ws + WS_PK);

    // z tiled f16 planes in the z_q output region (64 slabs * 16384 * 16 B = 16 MB)
    _Float16* zt = (_Float16*)zq;

    static bool attr_set = false;
    if (!attr_set) {
        hipFuncSetAttribute((const void*)vq_main,
                            hipFuncAttributeMaxDynamicSharedMemorySize, 49152);
        attr_set = true;
    }

    vq_prep_e<<<N_CODES / 4, 256, 0, stream>>>(emb, et, norms, loss);
    vq_prep_z<<<N_ROWS / 64, 256, 0, stream>>>(z, zt);
    vq_main<<<4096, 256, 49152, stream>>>(zt, et, norms, pk);
    vq_final<<<N_ROWS / 64, 512, 0, stream>>>(z, emb, pk, zq, loss, idx);
}

// Round 5
// 354.772 us; speedup vs baseline: 6.4337x; 6.4337x over previous
//
#include <hip/hip_runtime.h>
#include <stdint.h>

// z: [16,1024,256] fp32 -> N=16384 rows, D=256
// embedding: [8192,256] fp32 -> K=8192 codes
// out = [ z_q (4194304 f32) | loss (1 f32) | indices (16384 as f32) ]
#define N_ROWS   16384
#define DIM      256
#define N_CODES  8192
#define ZQ_ELEMS 4194304

typedef _Float16 f16x8 __attribute__((ext_vector_type(8)));
typedef _Float16 f16x4 __attribute__((ext_vector_type(4)));
typedef float    f32x16 __attribute__((ext_vector_type(16)));
typedef unsigned long long u64;

// ---- workspace (bytes): e_tiled 8 MB | norms 32 KB | pkeys 4 MB ----
#define WS_ET  0
#define WS_NRM (8388608)
#define WS_PK  (8421376)
// z tiled f16 planes live in the d_out z_q region (exactly 16 MB = 64 slabs
// x 16384 rows x 16 B), overwritten by vq_final after all reads (stream order).

static __device__ __forceinline__ void glds16(const void* gsrc, void* ldst) {
    __builtin_amdgcn_global_load_lds(
        (const __attribute__((address_space(1))) unsigned int*)gsrc,
        (__attribute__((address_space(3))) unsigned int*)ldst,
        16, 0, 0);
}

static __device__ __forceinline__ u64 packkey(float d, int c) {
    unsigned int u = __float_as_uint(d);
    u ^= ((unsigned int)((int)u >> 31)) | 0x80000000u;   // monotone float map
    return ((u64)u << 32) | (unsigned int)c;             // min => (dist, then idx)
}

// ---------------- prep E: norms + fragment-major tiled f16 hi/lo ----------------
// et 16-B units: slab = p*32 + dk*4 + f (p=plane, dk=K-chunk of 32, f=8-half group);
// unit addr = slab*8192 + code.
__global__ void vq_prep_e(const float* __restrict__ emb,
                          _Float16* __restrict__ et,
                          float* __restrict__ norms, float* __restrict__ loss_ptr) {
    if (blockIdx.x == 0 && threadIdx.x == 0) *loss_ptr = 0.0f;
    __shared__ _Float16 lh[4][256];
    __shared__ _Float16 ll[4][256];
    const int t = threadIdx.x, w = t >> 6, l = t & 63;
    const int code = blockIdx.x * 4 + w;
    float4 v = *(const float4*)(emb + (size_t)code * DIM + l * 4);
    float xs[4] = {v.x, v.y, v.z, v.w};
    f16x4 hh, lo;
    float s = 0.0f;
    #pragma unroll
    for (int i = 0; i < 4; ++i) {
        _Float16 h = (_Float16)xs[i];
        hh[i] = h;
        lo[i] = (_Float16)(xs[i] - (float)h);
        s += xs[i] * xs[i];
    }
    *(f16x4*)&lh[w][l * 4] = hh;
    *(f16x4*)&ll[w][l * 4] = lo;
    #pragma unroll
    for (int off = 32; off > 0; off >>= 1) s += __shfl_down(s, off, 64);
    if (l == 0) norms[code] = s;
    __syncthreads();
    const int p = t >> 7, g = t & 127;           // 2 planes x 4 codes x 32 slabs/plane
    const int cl = g & 3, dk = (g >> 2) & 7, f = g >> 5;
    f16x8 frag = (p == 0) ? *(const f16x8*)&lh[cl][dk * 32 + f * 8]
                          : *(const f16x8*)&ll[cl][dk * 32 + f * 8];
    const size_t slab = (size_t)(p * 32 + dk * 4 + f);
    *(f16x8*)(et + (slab * N_CODES + blockIdx.x * 4 + cl) * 8) = frag;
}

// ---------------- prep Z: fragment-major tiled f16 hi/lo (into zq region) ----------------
// zt 16-B units: slab = p*32 + dk*4 + f; unit addr = slab*16384 + row.
__global__ void vq_prep_z(const float* __restrict__ z, _Float16* __restrict__ zt) {
    __shared__ _Float16 ls[2][64][256];          // 64 KB
    const int t = threadIdx.x, w = t >> 6, l = t & 63;
    const int row0 = blockIdx.x * 64;
    #pragma unroll
    for (int j = 0; j < 16; ++j) {
        const int row = w * 16 + j;
        float4 v = *(const float4*)(z + (size_t)(row0 + row) * DIM + l * 4);
        float xs[4] = {v.x, v.y, v.z, v.w};
        f16x4 hh, lo;
        #pragma unroll
        for (int i = 0; i < 4; ++i) {
            _Float16 h = (_Float16)xs[i];
            hh[i] = h;
            lo[i] = (_Float16)(xs[i] - (float)h);
        }
        *(f16x4*)&ls[0][row][l * 4] = hh;
        *(f16x4*)&ls[1][row][l * 4] = lo;
    }
    __syncthreads();
    #pragma unroll
    for (int pass = 0; pass < 16; ++pass) {
        const int slab = pass * 4 + w;           // p*32 + dk*4 + f
        const int p = slab >> 5, dk = (slab >> 2) & 7, f = slab & 3;
        f16x8 frag = *(const f16x8*)&ls[p][l][dk * 32 + f * 8];
        *(f16x8*)(zt + ((size_t)slab * N_ROWS + row0 + l) * 8) = frag;
    }
}

// ---------------- main: m97 2-barrier K-loop, both tiles via glds ----------------
// grid 4096 = 128 row-blocks x 32 code-blocks; 4 waves; wave tile 64x128 (rt2 x ct4).
// LDS 49152 B: z [p2][f4][128 rows] @0, e [p2][f4][256 codes] @16384.
// launch_bounds(256,2): 2 waves/EU -> 256 VGPR budget. (256,3) forced the 128
// accumulator regs to spill to scratch -> 9.6 GB HBM traffic, 5x regression (R4).
__global__ __launch_bounds__(256, 2)
void vq_main(const _Float16* __restrict__ zt, const _Float16* __restrict__ et,
             const float* __restrict__ norms, u64* __restrict__ pkeys) {
    extern __shared__ char smem[];
    const int tid = threadIdx.x;
    const int w = tid >> 6, L = tid & 63, lo5 = L & 31, hi1 = L >> 5;
    const int rw = w & 1, cw = w >> 1;
    const int rb = blockIdx.x & 127, cb = blockIdx.x >> 7;
    const int row0 = rb * 128, code0 = cb * 256;

    f32x16 acc[2][4];
    #pragma unroll
    for (int rt = 0; rt < 2; ++rt)
        #pragma unroll
        for (int ct = 0; ct < 4; ++ct)
            #pragma unroll
            for (int e = 0; e < 16; ++e) acc[rt][ct][e] = 0.0f;

    for (int dk = 0; dk < 8; ++dk) {
        __syncthreads();                         // prior frag reads done
        // stage 48 KB: 48 glds of 1 KB, 12 per wave
        #pragma unroll
        for (int i = 0; i < 12; ++i) {
            const int idx = w * 12 + i;
            if (idx < 16) {                      // z tile: p2 x f4 x sub2
                const int p = idx >> 3, f = (idx >> 1) & 3, sub = idx & 1;
                const _Float16* g = zt + ((size_t)(p * 32 + dk * 4 + f) * N_ROWS
                                          + row0 + sub * 64 + L) * 8;
                glds16(g, smem + ((p * 4 + f) * 128 + sub * 64) * 16);
            } else {                             // e tile: p2 x f4 x sub4
                const int j = idx - 16;
                const int p = j >> 4, f = (j >> 2) & 3, sub = j & 3;
                const _Float16* g = et + ((size_t)(p * 32 + dk * 4 + f) * N_CODES
                                          + code0 + sub * 64 + L) * 8;
                glds16(g, smem + 16384 + ((p * 4 + f) * 256 + sub * 64) * 16);
            }
        }
        __syncthreads();                         // vmcnt drain -> tiles visible

        #pragma unroll
        for (int ks = 0; ks < 2; ++ks) {
            const int fs = ks * 2 + hi1;
            f16x8 ah[2], al[2], bh[4], bl[4];
            #pragma unroll
            for (int rt = 0; rt < 2; ++rt) {
                const int off = (fs * 128 + rw * 64 + rt * 32 + lo5) * 16;
                ah[rt] = *(const f16x8*)(smem + off);
                al[rt] = *(const f16x8*)(smem + 8192 + off);
            }
            #pragma unroll
            for (int ct = 0; ct < 4; ++ct) {
                const int off = 16384 + (fs * 256 + cw * 128 + ct * 32 + lo5) * 16;
                bh[ct] = *(const f16x8*)(smem + off);
                bl[ct] = *(const f16x8*)(smem + 16384 + off);
            }
            #pragma unroll
            for (int rt = 0; rt < 2; ++rt)
                #pragma unroll
                for (int ct = 0; ct < 4; ++ct) {
                    acc[rt][ct] = __builtin_amdgcn_mfma_f32_32x32x16_f16(ah[rt], bh[ct], acc[rt][ct], 0, 0, 0);
                    acc[rt][ct] = __builtin_amdgcn_mfma_f32_32x32x16_f16(ah[rt], bl[ct], acc[rt][ct], 0, 0, 0);
                    acc[rt][ct] = __builtin_amdgcn_mfma_f32_32x32x16_f16(al[rt], bh[ct], acc[rt][ct], 0, 0, 0);
                }
        }
    }

    // ---- argmin: pack -> u64, butterfly over 32 code-lanes, merge code halves ----
    __syncthreads();
    u64* sc = (u64*)smem;                        // [4][64]
    const int cbase = code0 + cw * 128 + lo5;
    float nrm[4];
    #pragma unroll
    for (int ct = 0; ct < 4; ++ct) nrm[ct] = norms[cbase + ct * 32];
    #pragma unroll
    for (int rt = 0; rt < 2; ++rt)
        #pragma unroll
        for (int reg = 0; reg < 16; ++reg) {
            u64 k = packkey(nrm[0] - 2.0f * acc[rt][0][reg], cbase);
            #pragma unroll
            for (int ct = 1; ct < 4; ++ct) {
                u64 o = packkey(nrm[ct] - 2.0f * acc[rt][ct][reg], cbase + ct * 32);
                if (o < k) k = o;
            }
            u64 o;
            o = __shfl_xor(k, 1, 64);  if (o < k) k = o;
            o = __shfl_xor(k, 2, 64);  if (o < k) k = o;
            o = __shfl_xor(k, 4, 64);  if (o < k) k = o;
            o = __shfl_xor(k, 8, 64);  if (o < k) k = o;
            o = __shfl_xor(k, 16, 64); if (o < k) k = o;
            if (lo5 == 0)
                sc[w * 64 + rt * 32 + (reg & 3) + 8 * (reg >> 2) + 4 * hi1] = k;
        }
    __syncthreads();
    if (tid < 128) {                             // row = tid; waves h and h+2 cover it
        const int h = tid >> 6, r6 = tid & 63;
        u64 k = sc[h * 64 + r6];
        u64 o = sc[(h + 2) * 64 + r6];
        if (o < k) k = o;
        pkeys[(size_t)cb * N_ROWS + row0 + tid] = k;
    }
}

// ---------------- final: merge 32 partials, idx, z_q gather, loss ----------------
__global__ __launch_bounds__(512)
void vq_final(const float* __restrict__ z, const float* __restrict__ emb,
              const u64* __restrict__ pkeys,
              float* __restrict__ zq_out, float* __restrict__ loss_out,
              float* __restrict__ idx_out) {
    __shared__ u64 kk[8][64];
    __shared__ int best[64];
    const int t = threadIdx.x;
    const int row0 = blockIdx.x * 64;
    const int r = t & 63, j = t >> 6;
    u64 k = ~0ULL;
    #pragma unroll
    for (int q = 0; q < 4; ++q) {
        u64 o = pkeys[(size_t)(j * 4 + q) * N_ROWS + row0 + r];
        if (o < k) k = o;
    }
    kk[j][r] = k;
    __syncthreads();
    if (t < 64) {
        u64 kb = kk[0][t];
        #pragma unroll
        for (int j2 = 1; j2 < 8; ++j2) if (kk[j2][t] < kb) kb = kk[j2][t];
        int code = (int)(kb & 0xFFFFFFFFu);
        best[t] = code;
        idx_out[row0 + t] = (float)code;
    }
    __syncthreads();
    const int wave = t >> 6, lane = t & 63;
    float lsum = 0.0f;
    #pragma unroll
    for (int rr = 0; rr < 8; ++rr) {
        const int rl = wave * 8 + rr;
        const int rg = row0 + rl;
        const int code = best[rl];
        float4 ev = *(const float4*)(emb + (size_t)code * DIM + lane * 4);
        float4 zv = *(const float4*)(z   + (size_t)rg   * DIM + lane * 4);
        float dx = ev.x - zv.x, dy = ev.y - zv.y;
        float dz = ev.z - zv.z, dw = ev.w - zv.w;
        lsum += dx * dx + dy * dy + dz * dz + dw * dw;
        *(float4*)(zq_out + (size_t)rg * DIM + lane * 4) = ev;
    }
    #pragma unroll
    for (int off = 32; off > 0; off >>= 1) lsum += __shfl_down(lsum, off, 64);
    if (lane == 0) atomicAdd(loss_out, lsum * (1.25f / (float)ZQ_ELEMS));
}

extern "C" void kernel_launch(void* const* d_in, const int* in_sizes, int n_in,
                              void* d_out, int out_size, void* d_ws, size_t ws_size,
                              hipStream_t stream) {
    const float* z   = (const float*)d_in[0];
    const float* emb = (const float*)d_in[1];
    float* out  = (float*)d_out;
    float* zq   = out;
    float* loss = out + ZQ_ELEMS;
    float* idx  = out + ZQ_ELEMS + 1;

    char* ws = (char*)d_ws;
    _Float16* et = (_Float16*)(ws + WS_ET);
    float* norms = (float*)(ws + WS_NRM);
    u64*   pk    = (u64*)(ws + WS_PK);

    // z tiled f16 planes in the z_q output region (64 slabs * 16384 * 16 B = 16 MB)
    _Float16* zt = (_Float16*)zq;

    static bool attr_set = false;
    if (!attr_set) {
        hipFuncSetAttribute((const void*)vq_main,
                            hipFuncAttributeMaxDynamicSharedMemorySize, 49152);
        attr_set = true;
    }

    vq_prep_e<<<N_CODES / 4, 256, 0, stream>>>(emb, et, norms, loss);
    vq_prep_z<<<N_ROWS / 64, 256, 0, stream>>>(z, zt);
    vq_main<<<4096, 256, 49152, stream>>>(zt, et, norms, pk);
    vq_final<<<N_ROWS / 64, 512, 0, stream>>>(z, emb, pk, zq, loss, idx);
}

// Round 6
// 317.286 us; speedup vs baseline: 7.1938x; 1.1181x over previous
//
#include <hip/hip_runtime.h>
#include <stdint.h>

// z: [16,1024,256] fp32 -> N=16384 rows, D=256
// embedding: [8192,256] fp32 -> K=8192 codes
// out = [ z_q (4194304 f32) | loss (1 f32) | indices (16384 as f32) ]
#define N_ROWS   16384
#define DIM      256
#define N_CODES  8192
#define ZQ_ELEMS 4194304

typedef _Float16 f16x8 __attribute__((ext_vector_type(8)));
typedef _Float16 f16x4 __attribute__((ext_vector_type(4)));
typedef float    f32x16 __attribute__((ext_vector_type(16)));
typedef unsigned long long u64;

// ---- workspace (bytes): e_tiled 8 MB | norms 32 KB | pkeys (2 splits) 256 KB ----
#define WS_ET  0
#define WS_NRM (8388608)
#define WS_PK  (8421376)
// z tiled f16 planes live in the d_out z_q region (exactly 16 MB = 64 slabs
// x 16384 rows x 16 B), overwritten by vq_final after all reads (stream order).

static __device__ __forceinline__ void glds16(const void* gsrc, void* ldst) {
    __builtin_amdgcn_global_load_lds(
        (const __attribute__((address_space(1))) unsigned int*)gsrc,
        (__attribute__((address_space(3))) unsigned int*)ldst,
        16, 0, 0);
}

static __device__ __forceinline__ u64 packkey(float d, int c) {
    unsigned int u = __float_as_uint(d);
    u ^= ((unsigned int)((int)u >> 31)) | 0x80000000u;   // monotone float map
    return ((u64)u << 32) | (unsigned int)c;             // min => (dist, then idx)
}

// ---------------- prep E: norms + fragment-major tiled f16 hi/lo ----------------
// et 16-B units: slab = p*32 + fg (p=plane, fg=k-octet 0..31); unit = slab*8192 + code.
__global__ void vq_prep_e(const float* __restrict__ emb,
                          _Float16* __restrict__ et,
                          float* __restrict__ norms, float* __restrict__ loss_ptr) {
    if (blockIdx.x == 0 && threadIdx.x == 0) *loss_ptr = 0.0f;
    __shared__ _Float16 lh[4][256];
    __shared__ _Float16 ll[4][256];
    const int t = threadIdx.x, w = t >> 6, l = t & 63;
    const int code = blockIdx.x * 4 + w;
    float4 v = *(const float4*)(emb + (size_t)code * DIM + l * 4);
    float xs[4] = {v.x, v.y, v.z, v.w};
    f16x4 hh, lo;
    float s = 0.0f;
    #pragma unroll
    for (int i = 0; i < 4; ++i) {
        _Float16 h = (_Float16)xs[i];
        hh[i] = h;
        lo[i] = (_Float16)(xs[i] - (float)h);
        s += xs[i] * xs[i];
    }
    *(f16x4*)&lh[w][l * 4] = hh;
    *(f16x4*)&ll[w][l * 4] = lo;
    #pragma unroll
    for (int off = 32; off > 0; off >>= 1) s += __shfl_down(s, off, 64);
    if (l == 0) norms[code] = s;
    __syncthreads();
    const int p = t >> 7, g = t & 127;           // 2 planes x 4 codes x 32 octets
    const int cl = g & 3, fg = g >> 2;
    f16x8 frag = (p == 0) ? *(const f16x8*)&lh[cl][fg * 8]
                          : *(const f16x8*)&ll[cl][fg * 8];
    const size_t slab = (size_t)(p * 32 + fg);
    *(f16x8*)(et + (slab * N_CODES + blockIdx.x * 4 + cl) * 8) = frag;
}

// ---------------- prep Z: fragment-major tiled f16 hi/lo (into zq region) ----------------
// zt 16-B units: slab = p*32 + fg; unit = slab*16384 + row.
__global__ void vq_prep_z(const float* __restrict__ z, _Float16* __restrict__ zt) {
    __shared__ _Float16 ls[2][64][256];          // 64 KB
    const int t = threadIdx.x, w = t >> 6, l = t & 63;
    const int row0 = blockIdx.x * 64;
    #pragma unroll
    for (int j = 0; j < 16; ++j) {
        const int row = w * 16 + j;
        float4 v = *(const float4*)(z + (size_t)(row0 + row) * DIM + l * 4);
        float xs[4] = {v.x, v.y, v.z, v.w};
        f16x4 hh, lo;
        #pragma unroll
        for (int i = 0; i < 4; ++i) {
            _Float16 h = (_Float16)xs[i];
            hh[i] = h;
            lo[i] = (_Float16)(xs[i] - (float)h);
        }
        *(f16x4*)&ls[0][row][l * 4] = hh;
        *(f16x4*)&ls[1][row][l * 4] = lo;
    }
    __syncthreads();
    #pragma unroll
    for (int pass = 0; pass < 16; ++pass) {
        const int slab = pass * 4 + w;           // p*32 + fg
        const int p = slab >> 5, fg = slab & 31;
        f16x8 frag = *(const f16x8*)&ls[p][l][fg * 8];
        *(f16x8*)(zt + ((size_t)slab * N_ROWS + row0 + l) * 8) = frag;
    }
}

// ---------------- main: barrier-free K-loop ----------------
// grid 256 = 128 row-blocks x 2 code-splits; 512 threads (8 waves, 2/SIMD).
// z-tile (128 rows x 256 k x 2 planes = 128 KB) persistent in LDS, staged once.
// E-fragments read directly from global (fragment-major et; L1/L2/LLC served).
// Wave tile: 64 rows (rt2) x 128 codes (ct4); waves: rw(2) x cw(4).
// Running argmin in LDS run[4 cw][128 rows] u64; one writer per (cw,row).
__global__ __launch_bounds__(512, 2)
void vq_main(const _Float16* __restrict__ zt, const _Float16* __restrict__ et,
             const float* __restrict__ norms, u64* __restrict__ pkeys) {
    extern __shared__ char smem[];
    _Float16* zs = (_Float16*)smem;              // unit: (slab*128 + row)*8 halves
    u64* run = (u64*)(smem + 131072);            // [4][128]

    const int tid = threadIdx.x;
    const int w = tid >> 6, L = tid & 63, lo5 = L & 31, hi1 = L >> 5;
    const int rw = w & 1, cw = w >> 1;
    const int rb = blockIdx.x >> 1, sp = blockIdx.x & 1;
    const int row0 = rb * 128, codeS = sp * 4096;

    // ---- stage z once: 128 glds of 1 KB (16 per wave) ----
    #pragma unroll
    for (int i = 0; i < 16; ++i) {
        const int idx = w * 16 + i;              // 0..127
        const int slab = idx >> 1, half = idx & 1;
        glds16(zt + ((size_t)slab * N_ROWS + row0 + half * 64 + L) * 8,
               smem + ((slab * 128 + half * 64 + L) << 4));
    }
    run[tid] = ~0ULL;                            // 512 entries = 4*128
    __syncthreads();

    for (int ci = 0; ci < 8; ++ci) {
        const int code0 = codeS + ci * 512 + cw * 128;   // wave's 128 codes

        f32x16 acc[2][4];
        #pragma unroll
        for (int rt = 0; rt < 2; ++rt)
            #pragma unroll
            for (int ct = 0; ct < 4; ++ct)
                #pragma unroll
                for (int e = 0; e < 16; ++e) acc[rt][ct][e] = 0.0f;

        #pragma unroll 2
        for (int ksg = 0; ksg < 16; ++ksg) {
            const int fg = ksg * 2 + hi1;        // k-octet 0..31
            // B frags direct from global (2 contiguous 512-B segments per load)
            f16x8 bh[4], bl[4];
            #pragma unroll
            for (int ct = 0; ct < 4; ++ct) {
                const size_t bo = ((size_t)fg * N_CODES + code0 + ct * 32 + lo5) * 8;
                bh[ct] = *(const f16x8*)(et + bo);
                bl[ct] = *(const f16x8*)(et + bo + (size_t)32 * N_CODES * 8);
            }
            // A frags from LDS
            f16x8 ah[2], al[2];
            #pragma unroll
            for (int rt = 0; rt < 2; ++rt) {
                const int ro = rw * 64 + rt * 32 + lo5;
                ah[rt] = *(const f16x8*)(zs + (size_t)(fg * 128 + ro) * 8);
                al[rt] = *(const f16x8*)(zs + (size_t)((fg + 32) * 128 + ro) * 8);
            }
            #pragma unroll
            for (int rt = 0; rt < 2; ++rt)
                #pragma unroll
                for (int ct = 0; ct < 4; ++ct) {
                    acc[rt][ct] = __builtin_amdgcn_mfma_f32_32x32x16_f16(ah[rt], bh[ct], acc[rt][ct], 0, 0, 0);
                    acc[rt][ct] = __builtin_amdgcn_mfma_f32_32x32x16_f16(ah[rt], bl[ct], acc[rt][ct], 0, 0, 0);
                    acc[rt][ct] = __builtin_amdgcn_mfma_f32_32x32x16_f16(al[rt], bh[ct], acc[rt][ct], 0, 0, 0);
                }
        }

        // ---- fold tile into LDS running argmin ----
        float nrm[4];
        #pragma unroll
        for (int ct = 0; ct < 4; ++ct) nrm[ct] = norms[code0 + ct * 32 + lo5];
        #pragma unroll
        for (int rt = 0; rt < 2; ++rt)
            #pragma unroll
            for (int reg = 0; reg < 16; ++reg) {
                u64 k = packkey(nrm[0] - 2.0f * acc[rt][0][reg], code0 + lo5);
                #pragma unroll
                for (int ct = 1; ct < 4; ++ct) {
                    u64 o = packkey(nrm[ct] - 2.0f * acc[rt][ct][reg],
                                    code0 + ct * 32 + lo5);
                    if (o < k) k = o;
                }
                u64 o;
                o = __shfl_xor(k, 1, 64);  if (o < k) k = o;
                o = __shfl_xor(k, 2, 64);  if (o < k) k = o;
                o = __shfl_xor(k, 4, 64);  if (o < k) k = o;
                o = __shfl_xor(k, 8, 64);  if (o < k) k = o;
                o = __shfl_xor(k, 16, 64); if (o < k) k = o;
                if (lo5 == 0) {
                    const int row = rw * 64 + rt * 32
                                  + (reg & 3) + 8 * (reg >> 2) + 4 * hi1;
                    u64* p = &run[cw * 128 + row];
                    if (k < *p) *p = k;          // sole writer for (cw,row)
                }
            }
    }

    __syncthreads();
    if (tid < 128) {
        u64 k = run[tid];
        #pragma unroll
        for (int c2 = 1; c2 < 4; ++c2) { u64 o = run[c2 * 128 + tid]; if (o < k) k = o; }
        pkeys[(size_t)sp * N_ROWS + row0 + tid] = k;
    }
}

// ---------------- final: merge 2 splits, idx, z_q gather, loss ----------------
__global__ __launch_bounds__(512)
void vq_final(const float* __restrict__ z, const float* __restrict__ emb,
              const u64* __restrict__ pkeys,
              float* __restrict__ zq_out, float* __restrict__ loss_out,
              float* __restrict__ idx_out) {
    __shared__ int best[64];
    const int t = threadIdx.x;
    const int row0 = blockIdx.x * 64;
    if (t < 64) {
        u64 k = pkeys[row0 + t];
        u64 o = pkeys[(size_t)N_ROWS + row0 + t];
        if (o < k) k = o;
        const int code = (int)(k & 0xFFFFFFFFu);
        best[t] = code;
        idx_out[row0 + t] = (float)code;
    }
    __syncthreads();
    const int wave = t >> 6, lane = t & 63;
    float lsum = 0.0f;
    #pragma unroll
    for (int rr = 0; rr < 8; ++rr) {
        const int rl = wave * 8 + rr;
        const int rg = row0 + rl;
        const int code = best[rl];
        float4 ev = *(const float4*)(emb + (size_t)code * DIM + lane * 4);
        float4 zv = *(const float4*)(z   + (size_t)rg   * DIM + lane * 4);
        float dx = ev.x - zv.x, dy = ev.y - zv.y;
        float dz = ev.z - zv.z, dw = ev.w - zv.w;
        lsum += dx * dx + dy * dy + dz * dz + dw * dw;
        *(float4*)(zq_out + (size_t)rg * DIM + lane * 4) = ev;
    }
    #pragma unroll
    for (int off = 32; off > 0; off >>= 1) lsum += __shfl_down(lsum, off, 64);
    if (lane == 0) atomicAdd(loss_out, lsum * (1.25f / (float)ZQ_ELEMS));
}

extern "C" void kernel_launch(void* const* d_in, const int* in_sizes, int n_in,
                              void* d_out, int out_size, void* d_ws, size_t ws_size,
                              hipStream_t stream) {
    const float* z   = (const float*)d_in[0];
    const float* emb = (const float*)d_in[1];
    float* out  = (float*)d_out;
    float* zq   = out;
    float* loss = out + ZQ_ELEMS;
    float* idx  = out + ZQ_ELEMS + 1;

    char* ws = (char*)d_ws;
    _Float16* et = (_Float16*)(ws + WS_ET);
    float* norms = (float*)(ws + WS_NRM);
    u64*   pk    = (u64*)(ws + WS_PK);

    // z tiled f16 planes in the z_q output region (64 slabs * 16384 * 16 B = 16 MB)
    _Float16* zt = (_Float16*)zq;

    static bool attr_set = false;
    if (!attr_set) {
        hipFuncSetAttribute((const void*)vq_main,
                            hipFuncAttributeMaxDynamicSharedMemorySize, 135168);
        attr_set = true;
    }

    vq_prep_e<<<N_CODES / 4, 256, 0, stream>>>(emb, et, norms, loss);
    vq_prep_z<<<N_ROWS / 64, 256, 0, stream>>>(z, zt);
    vq_main<<<256, 512, 135168, stream>>>(zt, et, norms, pk);
    vq_final<<<N_ROWS / 64, 512, 0, stream>>>(z, emb, pk, zq, loss, idx);
}